// Round 4
// baseline (437.011 us; speedup 1.0000x reference)
//
#include <hip/hip_runtime.h>
#include <hip/hip_bf16.h>

#define H 1024
#define V 50257
#define L 50

// ---------------------------------------------------------------------------
// K1: fused attention + comb.  grid 256 x 256.
// Every block redundantly computes scores+softmax (attn_w is L2-resident),
// builds [embedded | applied] in LDS, then computes 4 rows of comb + relu.
// ---------------------------------------------------------------------------
__global__ void attn_comb_kernel(const int* __restrict__ input_ids,
                                 const float* __restrict__ hidden,
                                 const float* __restrict__ enc,
                                 const float* __restrict__ emb,
                                 const float* __restrict__ attn_w,
                                 const float* __restrict__ attn_b,
                                 const float* __restrict__ comb_w,
                                 const float* __restrict__ comb_b,
                                 float* __restrict__ x1,
                                 float* __restrict__ out_attnw) {
    __shared__ __align__(16) float s_c[2 * H];   // [embedded | hidden->applied]
    __shared__ float s_sc[64];                   // raw scores
    __shared__ float s_w[64];                    // softmax weights
    const int tid = threadIdx.x;                 // 256
    const int wave = tid >> 6, lane = tid & 63;
    const int token = input_ids[0];

    float4* sc4 = (float4*)s_c;
    sc4[tid]       = ((const float4*)(emb + (size_t)token * H))[tid];
    sc4[256 + tid] = ((const float4*)hidden)[tid];
    __syncthreads();

    // scores: wave-per-row over L rows (dot of 512 float4 from LDS)
    for (int l = wave; l < L; l += 4) {
        const float4* r4 = (const float4*)(attn_w + (size_t)l * 2 * H);
        float acc = 0.f;
        #pragma unroll
        for (int kk = 0; kk < 8; ++kk) {
            int k = kk * 64 + lane;
            float4 a = r4[k], b = sc4[k];
            acc += a.x * b.x + a.y * b.y + a.z * b.z + a.w * b.w;
        }
        #pragma unroll
        for (int off = 32; off; off >>= 1) acc += __shfl_down(acc, off);
        if (lane == 0) s_sc[l] = acc + attn_b[l];
    }
    __syncthreads();

    if (tid == 0) {
        float m = s_sc[0];
        for (int l = 1; l < L; ++l) m = fmaxf(m, s_sc[l]);
        float s = 0.f;
        for (int l = 0; l < L; ++l) { float e = expf(s_sc[l] - m); s_w[l] = e; s += e; }
        float inv = 1.f / s;
        for (int l = 0; l < L; ++l) s_w[l] *= inv;
    }
    __syncthreads();

    // applied[j], thread owns 4 consecutive j; overwrite hidden half of LDS
    {
        float4 acc4 = make_float4(0.f, 0.f, 0.f, 0.f);
        for (int l = 0; l < L; ++l) {
            float w = s_w[l];
            float4 v = ((const float4*)enc)[l * 256 + tid];
            acc4.x += w * v.x; acc4.y += w * v.y; acc4.z += w * v.z; acc4.w += w * v.w;
        }
        sc4[256 + tid] = acc4;
        if (blockIdx.x == 0 && tid < L) out_attnw[tid] = s_w[tid];
    }
    __syncthreads();

    // comb: 4 rows/block, wave-per-row
    {
        const int r = blockIdx.x * 4 + wave;
        const float4* wr = (const float4*)(comb_w + (size_t)r * 2 * H);
        float acc = 0.f;
        #pragma unroll
        for (int kk = 0; kk < 8; ++kk) {
            int k = kk * 64 + lane;
            float4 a = wr[k], b = sc4[k];
            acc += a.x * b.x + a.y * b.y + a.z * b.z + a.w * b.w;
        }
        #pragma unroll
        for (int off = 32; off; off >>= 1) acc += __shfl_down(acc, off);
        if (lane == 0) x1[r] = fmaxf(acc + comb_b[r], 0.f);
    }
}

// ---------------------------------------------------------------------------
// K2/K3: GRU cell, split-K.  grid 1024 x 256 — one row per block, 4 waves
// each own a 256-float K-chunk of all 6 dots; LDS combine; t0 does gates.
// ---------------------------------------------------------------------------
__global__ void gru_kernel(const float* __restrict__ x,
                           const float* __restrict__ hprev,
                           const float* __restrict__ w_ih,
                           const float* __restrict__ w_hh,
                           const float* __restrict__ b_ih,
                           const float* __restrict__ b_hh,
                           float* __restrict__ h_out,
                           float* __restrict__ x_out,   // relu(h), nullable
                           float* __restrict__ h_copy)  // mirror to d_out, nullable
{
    __shared__ float s_red[4][8];
    const int tid = threadIdx.x;
    const int wave = tid >> 6, lane = tid & 63;
    const int i = blockIdx.x;                    // row 0..1023
    const int k = wave * 64 + lane;              // float4 index 0..255

    float4 xv = ((const float4*)x)[k];
    float4 hv = ((const float4*)hprev)[k];
    const float4* m0 = (const float4*)(w_ih + (size_t)i * H);
    const float4* m1 = (const float4*)(w_ih + (size_t)(H + i) * H);
    const float4* m2 = (const float4*)(w_ih + (size_t)(2 * H + i) * H);
    const float4* m3 = (const float4*)(w_hh + (size_t)i * H);
    const float4* m4 = (const float4*)(w_hh + (size_t)(H + i) * H);
    const float4* m5 = (const float4*)(w_hh + (size_t)(2 * H + i) * H);
    float4 t;
    float a0, a1, a2, a3, a4, a5;
    t = m0[k]; a0 = t.x * xv.x + t.y * xv.y + t.z * xv.z + t.w * xv.w;
    t = m1[k]; a1 = t.x * xv.x + t.y * xv.y + t.z * xv.z + t.w * xv.w;
    t = m2[k]; a2 = t.x * xv.x + t.y * xv.y + t.z * xv.z + t.w * xv.w;
    t = m3[k]; a3 = t.x * hv.x + t.y * hv.y + t.z * hv.z + t.w * hv.w;
    t = m4[k]; a4 = t.x * hv.x + t.y * hv.y + t.z * hv.z + t.w * hv.w;
    t = m5[k]; a5 = t.x * hv.x + t.y * hv.y + t.z * hv.z + t.w * hv.w;
    #pragma unroll
    for (int off = 32; off; off >>= 1) {
        a0 += __shfl_down(a0, off); a1 += __shfl_down(a1, off);
        a2 += __shfl_down(a2, off); a3 += __shfl_down(a3, off);
        a4 += __shfl_down(a4, off); a5 += __shfl_down(a5, off);
    }
    if (lane == 0) {
        s_red[wave][0] = a0; s_red[wave][1] = a1; s_red[wave][2] = a2;
        s_red[wave][3] = a3; s_red[wave][4] = a4; s_red[wave][5] = a5;
    }
    __syncthreads();
    if (tid == 0) {
        float g0 = 0, g1 = 0, g2 = 0, g3 = 0, g4 = 0, g5 = 0;
        #pragma unroll
        for (int w = 0; w < 4; ++w) {
            g0 += s_red[w][0]; g1 += s_red[w][1]; g2 += s_red[w][2];
            g3 += s_red[w][3]; g4 += s_red[w][4]; g5 += s_red[w][5];
        }
        float gxr = g0 + b_ih[i],         ghr = g3 + b_hh[i];
        float gxz = g1 + b_ih[H + i],     ghz = g4 + b_hh[H + i];
        float gxn = g2 + b_ih[2 * H + i], ghn = g5 + b_hh[2 * H + i];
        float r = 1.f / (1.f + expf(-(gxr + ghr)));
        float z = 1.f / (1.f + expf(-(gxz + ghz)));
        float n = tanhf(gxn + r * ghn);
        float hn = (1.f - z) * n + z * hprev[i];
        h_out[i] = hn;
        if (x_out)  x_out[i]  = fmaxf(hn, 0.f);
        if (h_copy) h_copy[i] = hn;
    }
}

// ---------------------------------------------------------------------------
// K4: vocab logits -> d_out. 16 rows/block (4 consecutive rows per wave,
// interleaved loads = 16 float4 in flight). Per-block partial exp-sum.
// ---------------------------------------------------------------------------
__global__ void logits_kernel(const float* __restrict__ out_w,
                              const float* __restrict__ out_b,
                              const float* __restrict__ h,
                              float* __restrict__ out,       // d_out[0..V)
                              float* __restrict__ partials) {
    __shared__ __align__(16) float s_h[H];
    __shared__ float s_part[4];
    const int tid = threadIdx.x;
    ((float4*)s_h)[tid] = ((const float4*)h)[tid];
    __syncthreads();

    const int wave = tid >> 6, lane = tid & 63;
    const float4* h4 = (const float4*)s_h;
    const int rbase = blockIdx.x * 16 + wave * 4;
    float acc[4] = {0.f, 0.f, 0.f, 0.f};

    if (rbase + 3 < V) {                          // fast path
        const float4* w0 = (const float4*)(out_w + (size_t)rbase * H);
        const float4* w1 = (const float4*)(out_w + (size_t)(rbase + 1) * H);
        const float4* w2 = (const float4*)(out_w + (size_t)(rbase + 2) * H);
        const float4* w3 = (const float4*)(out_w + (size_t)(rbase + 3) * H);
        #pragma unroll
        for (int kk = 0; kk < 4; ++kk) {
            int k = kk * 64 + lane;
            float4 b = h4[k];
            float4 a0 = w0[k], a1 = w1[k], a2 = w2[k], a3 = w3[k];
            acc[0] += a0.x * b.x + a0.y * b.y + a0.z * b.z + a0.w * b.w;
            acc[1] += a1.x * b.x + a1.y * b.y + a1.z * b.z + a1.w * b.w;
            acc[2] += a2.x * b.x + a2.y * b.y + a2.z * b.z + a2.w * b.w;
            acc[3] += a3.x * b.x + a3.y * b.y + a3.z * b.z + a3.w * b.w;
        }
    } else {                                      // boundary block
        #pragma unroll
        for (int r = 0; r < 4; ++r) {
            if (rbase + r < V) {
                const float4* wr = (const float4*)(out_w + (size_t)(rbase + r) * H);
                #pragma unroll
                for (int kk = 0; kk < 4; ++kk) {
                    int k = kk * 64 + lane;
                    float4 b = h4[k];
                    float4 a = wr[k];
                    acc[r] += a.x * b.x + a.y * b.y + a.z * b.z + a.w * b.w;
                }
            }
        }
    }
    #pragma unroll
    for (int off = 32; off; off >>= 1) {
        acc[0] += __shfl_down(acc[0], off); acc[1] += __shfl_down(acc[1], off);
        acc[2] += __shfl_down(acc[2], off); acc[3] += __shfl_down(acc[3], off);
    }
    if (lane == 0) {
        float psum = 0.f;
        #pragma unroll
        for (int r = 0; r < 4; ++r) {
            int v = rbase + r;
            if (v < V) {
                float lg = acc[r] + out_b[v];
                out[v] = lg;
                psum += expf(lg);
            }
        }
        s_part[wave] = psum;
    }
    __syncthreads();
    if (tid == 0)
        partials[blockIdx.x] = s_part[0] + s_part[1] + s_part[2] + s_part[3];
}

// K5: reduce partial exp-sums -> log-sum-exp scalar (single block)
__global__ void lse_kernel(const float* __restrict__ partials, int n,
                           float* __restrict__ lse) {
    __shared__ float red[256];
    const int tid = threadIdx.x;
    float s = 0.f;
    for (int i = tid; i < n; i += 256) s += partials[i];
    red[tid] = s;
    __syncthreads();
    for (int off = 128; off; off >>= 1) {
        if (tid < off) red[tid] += red[tid + off];
        __syncthreads();
    }
    if (tid == 0) *lse = logf(red[0]);
}

// K6: in-place log_probs[v] = logits[v] - lse
__global__ void sub_kernel(float* __restrict__ out,
                           const float* __restrict__ lse) {
    const int v = blockIdx.x * 256 + threadIdx.x;
    if (v < V) out[v] -= *lse;
}

// ---------------------------------------------------------------------------
extern "C" void kernel_launch(void* const* d_in, const int* in_sizes, int n_in,
                              void* d_out, int out_size, void* d_ws, size_t ws_size,
                              hipStream_t stream) {
    const int*   input_ids = (const int*)d_in[0];
    const float* hidden    = (const float*)d_in[1];
    const float* enc       = (const float*)d_in[2];
    const float* emb       = (const float*)d_in[3];
    const float* attn_w    = (const float*)d_in[4];
    const float* attn_b    = (const float*)d_in[5];
    const float* comb_w    = (const float*)d_in[6];
    const float* comb_b    = (const float*)d_in[7];
    const float* w_ih      = (const float*)d_in[8];
    const float* w_hh      = (const float*)d_in[9];
    const float* b_ih      = (const float*)d_in[10];
    const float* b_hh      = (const float*)d_in[11];
    const float* out_w     = (const float*)d_in[12];
    const float* out_b     = (const float*)d_in[13];

    float* out = (float*)d_out;            // [V | H | L]
    float* ws  = (float*)d_ws;
    float* ws_x1   = ws;                   // H
    float* ws_h1   = ws + 1024;            // H
    float* ws_x2   = ws + 2048;            // H
    float* ws_h2   = ws + 3072;            // H
    float* ws_part = ws + 4096;            // 3200
    float* ws_lse  = ws_part + 3200;       // 1

    const int nblk_logits = (V + 15) / 16; // 3142

    attn_comb_kernel<<<256, 256, 0, stream>>>(input_ids, hidden, enc, emb,
                                              attn_w, attn_b, comb_w, comb_b,
                                              ws_x1, out + V + H);
    gru_kernel<<<1024, 256, 0, stream>>>(ws_x1, hidden, w_ih, w_hh, b_ih, b_hh,
                                         ws_h1, ws_x2, nullptr);
    gru_kernel<<<1024, 256, 0, stream>>>(ws_x2, ws_h1, w_ih, w_hh, b_ih, b_hh,
                                         ws_h2, nullptr, out + V);
    logits_kernel<<<nblk_logits, 256, 0, stream>>>(out_w, out_b, ws_h2,
                                                   out, ws_part);
    lse_kernel<<<1, 256, 0, stream>>>(ws_part, nblk_logits, ws_lse);
    sub_kernel<<<(V + 255) / 256, 256, 0, stream>>>(out, ws_lse);
}